// Round 6
// baseline (892.849 us; speedup 1.0000x reference)
//
#include <hip/hip_runtime.h>
#include <math.h>

#define BATCH 2
#define NHEAD 16
#define SEQ   2048
#define HD    64
#define EMB   1024

// ---------------------------------------------------------------------------
// Eigen-AVX-emulating f32 GEMM: C[m,n] = (((p0+p1)+p2)+p3) + bias[n],
// where p_i = sequential k-ascending chain over panel i (kc=256) computed as
// mul-then-add (NO fma) — emulates jaxlib's prebuilt AVX (no-FMA) Eigen
// matmul thunk. __fmul_rn/__fadd_rn defeat hipcc fp-contract.
// MODE 0: out[m*EMB + n]                (row-major [4096,1024])
// MODE 1: out[((b*16+h)*SEQ+s)*HD + d]  (head layout, m=b*S+s, n=h*64+d)
// ---------------------------------------------------------------------------
template<int MODE>
__global__ __launch_bounds__(256)
void gemm_eigen(const float* __restrict__ A, const float* __restrict__ W,
                const float* __restrict__ bias, float* __restrict__ out) {
  __shared__ float As[16][68];
  __shared__ float Bs[16][68];
  const int m0 = blockIdx.x * 64;
  const int n0 = blockIdx.y * 64;
  const int t  = threadIdx.x;
  const int tx = t & 15, ty = t >> 4;
  const int ar = t >> 2, ac = (t & 3) * 4;
  const int br = t >> 4, bc = (t & 15) * 4;

  float tot[4][4] = {};
  float acc[4][4] = {};

  for (int p = 0; p < 4; ++p) {            // 4 balanced k-panels of 256
    for (int kt = 0; kt < 16; ++kt) {      // 16 LDS tiles of 16 per panel
      const int k0 = p * 256 + kt * 16;
      float4 av = *(const float4*)&A[(size_t)(m0 + ar) * EMB + k0 + ac];
      *(float4*)&Bs[br][bc] = *(const float4*)&W[(size_t)(k0 + br) * EMB + n0 + bc];
      As[ac + 0][ar] = av.x;
      As[ac + 1][ar] = av.y;
      As[ac + 2][ar] = av.z;
      As[ac + 3][ar] = av.w;
      __syncthreads();
#pragma unroll
      for (int kk = 0; kk < 16; ++kk) {
        float4 a = *(const float4*)&As[kk][ty * 4];
        float4 b = *(const float4*)&Bs[kk][tx * 4];
        float aa[4] = {a.x, a.y, a.z, a.w};
        float bb[4] = {b.x, b.y, b.z, b.w};
#pragma unroll
        for (int i = 0; i < 4; ++i)
#pragma unroll
          for (int j = 0; j < 4; ++j)
            acc[i][j] = __fadd_rn(acc[i][j], __fmul_rn(aa[i], bb[j]));
      }
      __syncthreads();
    }
    // panel boundary: tot += panel_chain (in panel order), reset panel acc
#pragma unroll
    for (int i = 0; i < 4; ++i)
#pragma unroll
      for (int j = 0; j < 4; ++j) {
        tot[i][j] = __fadd_rn(tot[i][j], acc[i][j]);
        acc[i][j] = 0.f;
      }
  }

#pragma unroll
  for (int i = 0; i < 4; ++i) {
    const int m = m0 + ty * 4 + i;
#pragma unroll
    for (int j = 0; j < 4; ++j) {
      const int n = n0 + tx * 4 + j;
      const float val = __fadd_rn(tot[i][j], bias[n]);
      if (MODE == 0) {
        out[(size_t)m * EMB + n] = val;
      } else {
        const int b = m >> 11, s = m & (SEQ - 1);
        const int h = n >> 6,  d = n & (HD - 1);
        out[((((size_t)b * NHEAD + h) * SEQ) + s) * HD + d] = val;
      }
    }
  }
}

// ---------------------------------------------------------------------------
// Pruning + sparse attention — all f32.
// Level-0 dot: sequential mul+add (Eigen-thunk emulation, matmul-shaped).
// Levels 1-4 + final dots: sequential FMA (XLA JIT'd emitter emulation).
// Top-k: serial scan over f32 LDS (value desc, index asc). No shuffles.
// ---------------------------------------------------------------------------
__global__ __launch_bounds__(256)
void prune_attn_f32(const float* __restrict__ q, const float* __restrict__ k,
                    const float* __restrict__ v, float* __restrict__ ctx) {
  const int blk  = blockIdx.x;
  const int qt   = blk & (SEQ / 4 - 1);   // 0..511
  const int bh   = blk >> 9;              // b*16+h
  const int wv   = threadIdx.x >> 6;
  const int lane = threadIdx.x & 63;
  const int s    = qt * 4 + wv;

  const float* kb = k + (size_t)bh * SEQ * HD;
  const float* vb = v + (size_t)bh * SEQ * HD;

  __shared__ float rep_lds[64][65];   // level-0 chunk reps
  __shared__ float q_lds[4][64];
  __shared__ float sc_lds[4][64];
  __shared__ int   top_lds[4][8];
  __shared__ short idxA[4][256];
  __shared__ short idxB[4][256];
  __shared__ float sfin_lds[4][16];
  __shared__ short kidx_lds[4][16];

  for (int i = threadIdx.x; i < 64 * 64; i += 256) {
    const int r = i >> 6, d = i & 63;
    rep_lds[r][d] = kb[(size_t)(r * 32 + 16) * HD + d];
  }
  q_lds[wv][lane] = q[((size_t)bh * SEQ + s) * HD + lane];
  __syncthreads();

  // ---- level 0: lane c scores chunk c — sequential MUL+ADD over d ----
  {
    float sc = 0.f;
#pragma unroll
    for (int d = 0; d < 64; ++d)
      sc = __fadd_rn(sc, __fmul_rn(q_lds[wv][d], rep_lds[lane][d]));
    sc_lds[wv][lane] = sc;
  }
  __syncthreads();

  // top-8 of 64: serial scan (value desc, index asc)
  for (int r = 0; r < 8; ++r) {
    float best = -INFINITY; int bi = 0;
#pragma unroll
    for (int c2 = 0; c2 < 64; ++c2) {
      const float vv = sc_lds[wv][c2];
      if (vv > best) { best = vv; bi = c2; }
    }
    if (lane == 0) { top_lds[wv][r] = bi; sc_lds[wv][bi] = -INFINITY; }
    __syncthreads();
  }

  // idx = (top0*32 + arange(32)), rank-major -> 256 entries
#pragma unroll
  for (int u = 0; u < 4; ++u) {
    const int p = lane * 4 + u;
    idxA[wv][p] = (short)(top_lds[wv][p >> 5] * 32 + (p & 31));
  }
  __syncthreads();

  short* cur = idxA[wv];
  short* nxt = idxB[wv];

  // ---- pruning levels cs = 16, 8, 4, 2 ----
#pragma unroll
  for (int cs = 16; cs >= 2; cs >>= 1) {
    // lane c (c<16) scores candidate chunk c: sequential 64-term FMA
    if (lane < 16) {
      const int rep = cur[lane * cs + (cs >> 1)];
      const float* kr = kb + (size_t)rep * HD;
      float sc = 0.f;
#pragma unroll
      for (int d = 0; d < 64; ++d)
        sc = fmaf(q_lds[wv][d], kr[d], sc);
      sc_lds[wv][lane] = sc;
    }
    __syncthreads();

    for (int r = 0; r < 8; ++r) {
      float best = -INFINITY; int bi = 0;
#pragma unroll
      for (int c2 = 0; c2 < 16; ++c2) {
        const float vv = sc_lds[wv][c2];
        if (vv > best) { best = vv; bi = c2; }
      }
      if (lane == 0) { top_lds[wv][r] = bi; sc_lds[wv][bi] = -INFINITY; }
      __syncthreads();
    }

    // expand: nxt[rr*cs + j] = cur[top[rr]*cs + j], rank-major
#pragma unroll
    for (int it = 0; it < 2; ++it) {
      const int p = it * 64 + lane;
      if (p < 8 * cs) {
        const int rr = p / cs;
        const int j  = p & (cs - 1);
        nxt[p] = cur[top_lds[wv][rr] * cs + j];
      }
    }
    __syncthreads();
    short* tmp = cur; cur = nxt; nxt = tmp;
  }

  // ---- final 16 keys: sequential FMA dot, scale 1/8 ----
  if (lane < 16) {
    const int kidx = cur[lane];
    const float* kr = kb + (size_t)kidx * HD;
    float sc = 0.f;
#pragma unroll
    for (int d = 0; d < 64; ++d)
      sc = fmaf(q_lds[wv][d], kr[d], sc);
    sfin_lds[wv][lane] = __fmul_rn(sc, 0.125f);
    kidx_lds[wv][lane] = (short)kidx;
  }
  __syncthreads();

  // ---- softmax over 16 (f32, per-weight division) + PV ----
  float sf[16];
#pragma unroll
  for (int j = 0; j < 16; ++j) sf[j] = sfin_lds[wv][j];
  float m = sf[0];
#pragma unroll
  for (int j = 1; j < 16; ++j) m = fmaxf(m, sf[j]);
  float e[16]; float sum = 0.f;
#pragma unroll
  for (int j = 0; j < 16; ++j) { e[j] = expf(sf[j] - m); sum = __fadd_rn(sum, e[j]); }

  float acc = 0.f;
#pragma unroll
  for (int j = 0; j < 16; ++j) {
    const float aj = __fdiv_rn(e[j], sum);
    acc = fmaf(aj, vb[(size_t)kidx_lds[wv][j] * HD + lane], acc);
  }

  const int b = bh >> 4, h = bh & 15;
  ctx[(((size_t)b * SEQ) + s) * EMB + h * HD + lane] = acc;
}

// ---------------------------------------------------------------------------
extern "C" void kernel_launch(void* const* d_in, const int* in_sizes, int n_in,
                              void* d_out, int out_size, void* d_ws, size_t ws_size,
                              hipStream_t stream) {
  const float* x  = (const float*)d_in[0];
  const float* Wq = (const float*)d_in[1];
  const float* bq = (const float*)d_in[2];
  const float* Wk = (const float*)d_in[3];
  const float* bk = (const float*)d_in[4];
  const float* Wv = (const float*)d_in[5];
  const float* bv = (const float*)d_in[6];
  const float* Wo = (const float*)d_in[7];
  const float* bo = (const float*)d_in[8];
  float* out = (float*)d_out;

  const size_t SZ = (size_t)BATCH * NHEAD * SEQ * HD;  // 4,194,304
  float* qw = (float*)d_ws;
  float* kw = qw + SZ;
  float* vw = kw + SZ;
  float* cw = vw + SZ;   // ctx in [B,S,E] layout

  dim3 g(64, 16), blk(256);
  gemm_eigen<1><<<g, blk, 0, stream>>>(x, Wq, bq, qw);
  gemm_eigen<1><<<g, blk, 0, stream>>>(x, Wk, bk, kw);
  gemm_eigen<1><<<g, blk, 0, stream>>>(x, Wv, bv, vw);
  prune_attn_f32<<<dim3(BATCH * NHEAD * (SEQ / 4)), blk, 0, stream>>>(qw, kw, vw, cw);
  gemm_eigen<0><<<g, blk, 0, stream>>>(cw, Wo, bo, out);
}